// Round 8
// baseline (22.088 us; speedup 1.0000x reference)
//
#include <hip/hip_runtime.h>

#define BATCH 64
#define IMH 256
#define IMW 256
#define CIN 512
#define NH 128
#define BPB 4                 // blocks per batch
#define ROWS_PB (IMH / BPB)   // 64 image rows per block

// Single fused kernel, 256 blocks x 1024 threads (16 waves) = 1 block/CU.
// Phase P: prefetch this thread's 4 input-image rows into registers (x-reads
//          are independent of the MLP -> overlap their latency with phase A).
// Phase A: redundant per-block MLP head (4 blocks/batch = minimal full-chip
//          redundancy; 325 KB weights/CU is the irreducible L2 term). Each
//          of 16 waves computes 8 rows at once: lane=(rsub,ksub), float4
//          coalesced weight loads, 3 shfl_xor reduce.
// Phase B: pure-VALU smooth-max on the prefetched registers; 2 output rows
//          x 8 px per thread (2.5 exps/px), float4 stores.
__global__ __launch_bounds__(1024) void fused_kernel(
        const float* __restrict__ x,
        const float* __restrict__ features,
        const float* __restrict__ W0, const float* __restrict__ b0,
        const float* __restrict__ W1, const float* __restrict__ b1,
        const float* __restrict__ W2, const float* __restrict__ b2,
        float* __restrict__ out) {
    const int t     = threadIdx.x;    // 0..1023
    const int wave  = t >> 6;         // 0..15
    const int lane  = t & 63;
    const int batch = blockIdx.x >> 2;
    const int rgrp  = blockIdx.x & 3;

    const int rsub = lane >> 3;       // 0..7 row within 8-row group
    const int ksub = lane & 7;        // 0..7 k-chunk

    __shared__ float f[CIN];
    __shared__ float h0[NH];
    __shared__ float h1[NH];
    __shared__ float akl[10];

    // ---------------- phase P: prefetch pixel rows into registers --------
    const int r0 = rgrp * ROWS_PB + ((t >> 5) << 1);   // even out-row
    const int c0 = (t & 31) << 3;                      // 0,8,...,248
    const float* xb = x + ((size_t)batch << 16);

    float pr[4][10];
    #pragma unroll
    for (int j = 0; j < 4; ++j) {
        const int rr = r0 - 1 + j;
        if ((unsigned)rr < (unsigned)IMH) {
            const float* xr = xb + rr * IMW;
            const float4 v0 = *reinterpret_cast<const float4*>(xr + c0);
            const float4 v1 = *reinterpret_cast<const float4*>(xr + c0 + 4);
            pr[j][0] = (c0 == 0)       ? 0.f : xr[c0 - 1];
            pr[j][1] = v0.x; pr[j][2] = v0.y; pr[j][3] = v0.z; pr[j][4] = v0.w;
            pr[j][5] = v1.x; pr[j][6] = v1.y; pr[j][7] = v1.z; pr[j][8] = v1.w;
            pr[j][9] = (c0 == IMW - 8) ? 0.f : xr[c0 + 8];
        } else {
            #pragma unroll
            for (int q = 0; q < 10; ++q) pr[j][q] = 0.f;
        }
    }

    // ---------------- phase A: MLP ----------------
    if (t < CIN) f[t] = features[batch * CIN + t];
    __syncthreads();

    const float4* f4 = reinterpret_cast<const float4*>(f);

    // layer 0: wave w owns rows 8w..8w+7; dot over 512 (16 float4 passes)
    {
        const int row = wave * 8 + rsub;
        const float4* w4 = reinterpret_cast<const float4*>(W0) + row * (CIN / 4) + ksub;
        float acc = 0.f;
        #pragma unroll
        for (int pass = 0; pass < 16; ++pass) {
            const float4 wv = w4[pass * 8];
            const float4 fv = f4[ksub + pass * 8];
            acc = fmaf(wv.x, fv.x, acc);
            acc = fmaf(wv.y, fv.y, acc);
            acc = fmaf(wv.z, fv.z, acc);
            acc = fmaf(wv.w, fv.w, acc);
        }
        acc += __shfl_xor(acc, 1);
        acc += __shfl_xor(acc, 2);
        acc += __shfl_xor(acc, 4);
        if (ksub == 0) h0[row] = fmaxf(acc + b0[row], 0.f);
    }
    __syncthreads();

    // layer 1: dot over 128 (4 float4 passes)
    const float4* h04 = reinterpret_cast<const float4*>(h0);
    {
        const int row = wave * 8 + rsub;
        const float4* w4 = reinterpret_cast<const float4*>(W1) + row * (NH / 4) + ksub;
        float acc = 0.f;
        #pragma unroll
        for (int pass = 0; pass < 4; ++pass) {
            const float4 wv = w4[pass * 8];
            const float4 hv = h04[ksub + pass * 8];
            acc = fmaf(wv.x, hv.x, acc);
            acc = fmaf(wv.y, hv.y, acc);
            acc = fmaf(wv.z, hv.z, acc);
            acc = fmaf(wv.w, hv.w, acc);
        }
        acc += __shfl_xor(acc, 1);
        acc += __shfl_xor(acc, 2);
        acc += __shfl_xor(acc, 4);
        if (ksub == 0) h1[row] = fmaxf(acc + b1[row], 0.f);
    }
    __syncthreads();

    // head: 10 rows; wave 0 -> rows 0..7, wave 1 -> rows 8..9
    const int hrow = wave * 8 + rsub;
    if (wave < 2 && hrow < 10) {
        const float4* h14 = reinterpret_cast<const float4*>(h1);
        const float4* w4  = reinterpret_cast<const float4*>(W2) + hrow * (NH / 4) + ksub;
        float acc = 0.f;
        #pragma unroll
        for (int pass = 0; pass < 4; ++pass) {
            const float4 wv = w4[pass * 8];
            const float4 hv = h14[ksub + pass * 8];
            acc = fmaf(wv.x, hv.x, acc);
            acc = fmaf(wv.y, hv.y, acc);
            acc = fmaf(wv.z, hv.z, acc);
            acc = fmaf(wv.w, hv.w, acc);
        }
        acc += __shfl_xor(acc, 1);
        acc += __shfl_xor(acc, 2);
        acc += __shfl_xor(acc, 4);
        if (ksub == 0) {
            float beta = acc + b2[hrow];
            if (hrow == 0) {
                akl[0] = beta;                           // alpha
            } else {
                beta += (hrow == 5) ? 5.f : -5.f;        // identity bias (center +5)
                akl[hrow] = 1.f / (1.f + __expf(-beta)); // sigmoid
            }
        }
    }
    __syncthreads();

    const float al2 = akl[0] * 1.44269504088896f;  // alpha * log2(e)
    float kern[9];
    #pragma unroll
    for (int i = 0; i < 9; ++i) kern[i] = akl[1 + i];

    // ---------------- phase B: smooth-max on registers ----------------
    float num0[8], den0[8], num1[8], den1[8];
    #pragma unroll
    for (int i = 0; i < 8; ++i) {
        num0[i] = 0.f; den0[i] = 0.f;
        num1[i] = 0.f; den1[i] = 0.f;
    }

    // input row j feeds out-row0 (kern row j, j<3) and out-row1 (kern row j-1, j>0)
    #pragma unroll
    for (int j = 0; j < 4; ++j) {
        float e[10];
        #pragma unroll
        for (int q = 0; q < 10; ++q) e[q] = exp2f(al2 * pr[j][q]);

        if (j < 3) {
            const int kr = 3 * j;
            #pragma unroll
            for (int i = 0; i < 8; ++i) {
                #pragma unroll
                for (int dx = 0; dx < 3; ++dx) {
                    const float wt = e[i + dx] * kern[kr + dx];
                    num0[i] = fmaf(pr[j][i + dx], wt, num0[i]);
                    den0[i] += wt;
                }
            }
        }
        if (j > 0) {
            const int kr = 3 * (j - 1);
            #pragma unroll
            for (int i = 0; i < 8; ++i) {
                #pragma unroll
                for (int dx = 0; dx < 3; ++dx) {
                    const float wt = e[i + dx] * kern[kr + dx];
                    num1[i] = fmaf(pr[j][i + dx], wt, num1[i]);
                    den1[i] += wt;
                }
            }
        }
    }

    float* ob = out + ((size_t)batch << 16) + r0 * IMW + c0;
    float4 o0, o1;
    o0.x = num0[0] * __builtin_amdgcn_rcpf(den0[0]);
    o0.y = num0[1] * __builtin_amdgcn_rcpf(den0[1]);
    o0.z = num0[2] * __builtin_amdgcn_rcpf(den0[2]);
    o0.w = num0[3] * __builtin_amdgcn_rcpf(den0[3]);
    o1.x = num0[4] * __builtin_amdgcn_rcpf(den0[4]);
    o1.y = num0[5] * __builtin_amdgcn_rcpf(den0[5]);
    o1.z = num0[6] * __builtin_amdgcn_rcpf(den0[6]);
    o1.w = num0[7] * __builtin_amdgcn_rcpf(den0[7]);
    *reinterpret_cast<float4*>(ob)     = o0;
    *reinterpret_cast<float4*>(ob + 4) = o1;

    float4 p0, p1;
    p0.x = num1[0] * __builtin_amdgcn_rcpf(den1[0]);
    p0.y = num1[1] * __builtin_amdgcn_rcpf(den1[1]);
    p0.z = num1[2] * __builtin_amdgcn_rcpf(den1[2]);
    p0.w = num1[3] * __builtin_amdgcn_rcpf(den1[3]);
    p1.x = num1[4] * __builtin_amdgcn_rcpf(den1[4]);
    p1.y = num1[5] * __builtin_amdgcn_rcpf(den1[5]);
    p1.z = num1[6] * __builtin_amdgcn_rcpf(den1[6]);
    p1.w = num1[7] * __builtin_amdgcn_rcpf(den1[7]);
    *reinterpret_cast<float4*>(ob + IMW)     = p0;
    *reinterpret_cast<float4*>(ob + IMW + 4) = p1;
}

extern "C" void kernel_launch(void* const* d_in, const int* in_sizes, int n_in,
                              void* d_out, int out_size, void* d_ws, size_t ws_size,
                              hipStream_t stream) {
    const float* x        = (const float*)d_in[0];
    const float* features = (const float*)d_in[1];
    const float* W0       = (const float*)d_in[2];
    const float* b0       = (const float*)d_in[3];
    const float* W1       = (const float*)d_in[4];
    const float* b1       = (const float*)d_in[5];
    const float* W2       = (const float*)d_in[6];
    const float* b2       = (const float*)d_in[7];
    float* out = (float*)d_out;

    fused_kernel<<<BATCH * BPB, 1024, 0, stream>>>(
        x, features, W0, b0, W1, b1, W2, b2, out);
}

// Round 9
// 19.954 us; speedup vs baseline: 1.1070x; 1.1070x over previous
//
#include <hip/hip_runtime.h>

#define BATCH 64
#define IMH 256
#define IMW 256
#define CIN 512
#define NH 128
#define BPB 4                 // blocks per batch
#define ROWS_PB (IMH / BPB)   // 64 image rows per block
#define XT_ROWS (ROWS_PB + 2) // staged rows incl. top/bottom halo

typedef __attribute__((address_space(3))) void       lds_void;
typedef __attribute__((address_space(1))) const void glb_void;

// Single fused kernel, 256 blocks x 1024 threads (16 waves) = 1 block/CU.
//
// Phase S: async-stage this block's 66-row x tile into LDS via
//          global_load_lds (no VGPR cost — round 8 showed register prefetch
//          spills at the 128-VGPR/1024-thread cap). Issued AFTER the f-
//          barrier so the loads fly during layer 0's weight streaming; the
//          compiler's vmcnt(0) drain at the next barrier lands ~1.4 us later.
// Phase A: redundant per-block MLP head (1 block/CU -> 325 KB weights/CU
//          through the L1 port, the irreducible term). 16 waves x 8 rows,
//          lane=(rsub,ksub), float4 weight loads, 3 shfl_xor reduce.
// Phase B: smooth-max from LDS; halo rows are pre-zeroed so no row bounds
//          checks. 2 output rows x 8 px per thread, 2.5 exps/px.
__global__ __launch_bounds__(1024) void fused_kernel(
        const float* __restrict__ x,
        const float* __restrict__ features,
        const float* __restrict__ W0, const float* __restrict__ b0,
        const float* __restrict__ W1, const float* __restrict__ b1,
        const float* __restrict__ W2, const float* __restrict__ b2,
        float* __restrict__ out) {
    const int t     = threadIdx.x;    // 0..1023
    const int wave  = t >> 6;         // 0..15
    const int lane  = t & 63;
    const int batch = blockIdx.x >> 2;
    const int rgrp  = blockIdx.x & 3;

    const int rsub = lane >> 3;       // 0..7 row within 8-row group
    const int ksub = lane & 7;        // 0..7 k-chunk

    __shared__ float xt[XT_ROWS * IMW];   // 67.6 KB
    __shared__ float f[CIN];
    __shared__ float h0[NH];
    __shared__ float h1[NH];
    __shared__ float akl[10];

    // ---- load features, barrier BEFORE issuing async staging ----
    if (t < CIN) f[t] = features[batch * CIN + t];
    __syncthreads();

    // ---------------- phase S: async-stage x tile into LDS ----------------
    // wave w stages rows w, w+16, w+32, w+48, (w<2: w+64): one
    // global_load_lds_dwordx4 per row (64 lanes x 16 B = 1 KB = 1 row).
    {
        const float* xb   = x + ((size_t)batch << 16);
        const int    rbase = rgrp * ROWS_PB - 1;
        for (int idx = wave; idx < XT_ROWS; idx += 16) {
            const int rr  = rbase + idx;
            float*    dst = &xt[idx * IMW];
            if ((unsigned)rr < (unsigned)IMH) {
                const float* src = xb + rr * IMW + lane * 4;
                __builtin_amdgcn_global_load_lds((glb_void*)src, (lds_void*)dst,
                                                 16, 0, 0);
            } else {
                // zero halo row (rgrp 0 top, rgrp 3 bottom)
                float4 z = {0.f, 0.f, 0.f, 0.f};
                *reinterpret_cast<float4*>(dst + lane * 4) = z;
            }
        }
    }

    // ---------------- phase A: MLP ----------------
    const float4* f4 = reinterpret_cast<const float4*>(f);

    // layer 0: wave w owns rows 8w..8w+7; dot over 512 (16 float4 passes)
    {
        const int row = wave * 8 + rsub;
        const float4* w4 = reinterpret_cast<const float4*>(W0) + row * (CIN / 4) + ksub;
        float acc = 0.f;
        #pragma unroll
        for (int pass = 0; pass < 16; ++pass) {
            const float4 wv = w4[pass * 8];
            const float4 fv = f4[ksub + pass * 8];
            acc = fmaf(wv.x, fv.x, acc);
            acc = fmaf(wv.y, fv.y, acc);
            acc = fmaf(wv.z, fv.z, acc);
            acc = fmaf(wv.w, fv.w, acc);
        }
        acc += __shfl_xor(acc, 1);
        acc += __shfl_xor(acc, 2);
        acc += __shfl_xor(acc, 4);
        if (ksub == 0) h0[row] = fmaxf(acc + b0[row], 0.f);
    }
    __syncthreads();   // also drains staging vmcnt (overlapped with layer 0)

    // layer 1: dot over 128 (4 float4 passes)
    const float4* h04 = reinterpret_cast<const float4*>(h0);
    {
        const int row = wave * 8 + rsub;
        const float4* w4 = reinterpret_cast<const float4*>(W1) + row * (NH / 4) + ksub;
        float acc = 0.f;
        #pragma unroll
        for (int pass = 0; pass < 4; ++pass) {
            const float4 wv = w4[pass * 8];
            const float4 hv = h04[ksub + pass * 8];
            acc = fmaf(wv.x, hv.x, acc);
            acc = fmaf(wv.y, hv.y, acc);
            acc = fmaf(wv.z, hv.z, acc);
            acc = fmaf(wv.w, hv.w, acc);
        }
        acc += __shfl_xor(acc, 1);
        acc += __shfl_xor(acc, 2);
        acc += __shfl_xor(acc, 4);
        if (ksub == 0) h1[row] = fmaxf(acc + b1[row], 0.f);
    }
    __syncthreads();

    // head: 10 rows; wave 0 -> rows 0..7, wave 1 -> rows 8..9
    const int hrow = wave * 8 + rsub;
    if (wave < 2 && hrow < 10) {
        const float4* h14 = reinterpret_cast<const float4*>(h1);
        const float4* w4  = reinterpret_cast<const float4*>(W2) + hrow * (NH / 4) + ksub;
        float acc = 0.f;
        #pragma unroll
        for (int pass = 0; pass < 4; ++pass) {
            const float4 wv = w4[pass * 8];
            const float4 hv = h14[ksub + pass * 8];
            acc = fmaf(wv.x, hv.x, acc);
            acc = fmaf(wv.y, hv.y, acc);
            acc = fmaf(wv.z, hv.z, acc);
            acc = fmaf(wv.w, hv.w, acc);
        }
        acc += __shfl_xor(acc, 1);
        acc += __shfl_xor(acc, 2);
        acc += __shfl_xor(acc, 4);
        if (ksub == 0) {
            float beta = acc + b2[hrow];
            if (hrow == 0) {
                akl[0] = beta;                           // alpha
            } else {
                beta += (hrow == 5) ? 5.f : -5.f;        // identity bias (center +5)
                akl[hrow] = 1.f / (1.f + __expf(-beta)); // sigmoid
            }
        }
    }
    __syncthreads();

    const float al2 = akl[0] * 1.44269504088896f;  // alpha * log2(e)
    float kern[9];
    #pragma unroll
    for (int i = 0; i < 9; ++i) kern[i] = akl[1 + i];

    // ---------------- phase B: smooth-max from LDS ----------------
    // 1024 threads = 32 thread-rows x 32 col-segments; 2 rows x 8 px each.
    const int tr  = (t >> 5) << 1;                 // even local out-row offset
    const int c0  = (t & 31) << 3;                 // 0,8,...,248
    const int r0  = rgrp * ROWS_PB + tr;           // global out-row

    float num0[8], den0[8], num1[8], den1[8];
    #pragma unroll
    for (int i = 0; i < 8; ++i) {
        num0[i] = 0.f; den0[i] = 0.f;
        num1[i] = 0.f; den1[i] = 0.f;
    }

    // local rows tr..tr+3 = global rows r0-1..r0+2 (halo pre-zeroed).
    // row j feeds out-row0 (kern row j, j<3) and out-row1 (kern row j-1, j>0)
    #pragma unroll
    for (int j = 0; j < 4; ++j) {
        const float* xr = &xt[(tr + j) * IMW];
        float p[10];
        const float4 v0 = *reinterpret_cast<const float4*>(xr + c0);
        const float4 v1 = *reinterpret_cast<const float4*>(xr + c0 + 4);
        p[0] = (c0 == 0)       ? 0.f : xr[c0 - 1];
        p[1] = v0.x; p[2] = v0.y; p[3] = v0.z; p[4] = v0.w;
        p[5] = v1.x; p[6] = v1.y; p[7] = v1.z; p[8] = v1.w;
        p[9] = (c0 == IMW - 8) ? 0.f : xr[c0 + 8];

        float e[10];
        #pragma unroll
        for (int q = 0; q < 10; ++q) e[q] = exp2f(al2 * p[q]);

        if (j < 3) {
            const int kr = 3 * j;
            #pragma unroll
            for (int i = 0; i < 8; ++i) {
                #pragma unroll
                for (int dx = 0; dx < 3; ++dx) {
                    const float wt = e[i + dx] * kern[kr + dx];
                    num0[i] = fmaf(p[i + dx], wt, num0[i]);
                    den0[i] += wt;
                }
            }
        }
        if (j > 0) {
            const int kr = 3 * (j - 1);
            #pragma unroll
            for (int i = 0; i < 8; ++i) {
                #pragma unroll
                for (int dx = 0; dx < 3; ++dx) {
                    const float wt = e[i + dx] * kern[kr + dx];
                    num1[i] = fmaf(p[i + dx], wt, num1[i]);
                    den1[i] += wt;
                }
            }
        }
    }

    float* ob = out + ((size_t)batch << 16) + r0 * IMW + c0;
    float4 o0, o1;
    o0.x = num0[0] * __builtin_amdgcn_rcpf(den0[0]);
    o0.y = num0[1] * __builtin_amdgcn_rcpf(den0[1]);
    o0.z = num0[2] * __builtin_amdgcn_rcpf(den0[2]);
    o0.w = num0[3] * __builtin_amdgcn_rcpf(den0[3]);
    o1.x = num0[4] * __builtin_amdgcn_rcpf(den0[4]);
    o1.y = num0[5] * __builtin_amdgcn_rcpf(den0[5]);
    o1.z = num0[6] * __builtin_amdgcn_rcpf(den0[6]);
    o1.w = num0[7] * __builtin_amdgcn_rcpf(den0[7]);
    *reinterpret_cast<float4*>(ob)     = o0;
    *reinterpret_cast<float4*>(ob + 4) = o1;

    float4 p0, p1;
    p0.x = num1[0] * __builtin_amdgcn_rcpf(den1[0]);
    p0.y = num1[1] * __builtin_amdgcn_rcpf(den1[1]);
    p0.z = num1[2] * __builtin_amdgcn_rcpf(den1[2]);
    p0.w = num1[3] * __builtin_amdgcn_rcpf(den1[3]);
    p1.x = num1[4] * __builtin_amdgcn_rcpf(den1[4]);
    p1.y = num1[5] * __builtin_amdgcn_rcpf(den1[5]);
    p1.z = num1[6] * __builtin_amdgcn_rcpf(den1[6]);
    p1.w = num1[7] * __builtin_amdgcn_rcpf(den1[7]);
    *reinterpret_cast<float4*>(ob + IMW)     = p0;
    *reinterpret_cast<float4*>(ob + IMW + 4) = p1;
}

extern "C" void kernel_launch(void* const* d_in, const int* in_sizes, int n_in,
                              void* d_out, int out_size, void* d_ws, size_t ws_size,
                              hipStream_t stream) {
    const float* x        = (const float*)d_in[0];
    const float* features = (const float*)d_in[1];
    const float* W0       = (const float*)d_in[2];
    const float* b0       = (const float*)d_in[3];
    const float* W1       = (const float*)d_in[4];
    const float* b1       = (const float*)d_in[5];
    const float* W2       = (const float*)d_in[6];
    const float* b2       = (const float*)d_in[7];
    float* out = (float*)d_out;

    fused_kernel<<<BATCH * BPB, 1024, 0, stream>>>(
        x, features, W0, b0, W1, b1, W2, b2, out);
}